// Round 9
// baseline (245.199 us; speedup 1.0000x reference)
//
#include <hip/hip_runtime.h>
#include <math.h>

#define NATOMS 128
#define NALIGN 64
#define TPB    64                 // ONE wave per block: no __syncthreads anywhere
#define FRW    32                 // frames per wave
#define TILES  (FRW / 2)          // 16 tiles of 2 frames (192 float4) each
#define PF     4                  // register prefetch depth (tiles)

// Wave-internal LDS ordering fence: waits DS ops only (vmcnt untouched, so
// global prefetches stay in flight). sched_barrier(0) pins the compiler
// (rule: hipcc may hoist dependent ops past inline-asm waitcnt otherwise).
#define LDS_FENCE() do { asm volatile("s_waitcnt lgkmcnt(0)" ::: "memory"); \
                         __builtin_amdgcn_sched_barrier(0); } while (0)

// Branchless Jacobi rotation on symmetric 3x3 for pair (p,q); third index r.
// Tiny/zero apq degenerates to identity rotation via clamped denominator.
#define JACOBI_ROT(app, aqq, apq, arp, arq, pcol, qcol)                 \
  {                                                                     \
    float _apq = (apq);                                                 \
    float _den = 2.0f * _apq;                                           \
    _den = copysignf(fmaxf(fabsf(_den), 1e-30f), _den);                 \
    float _tau = ((aqq) - (app)) / _den;                                \
    float _t = (_tau >= 0.0f ? 1.0f : -1.0f) /                          \
               (fabsf(_tau) + sqrtf(1.0f + _tau * _tau));               \
    float _c = rsqrtf(1.0f + _t * _t);                                  \
    float _s = _t * _c;                                                 \
    (app) -= _t * _apq;                                                 \
    (aqq) += _t * _apq;                                                 \
    (apq) = 0.0f;                                                       \
    float _rp = (arp), _rq = (arq);                                     \
    (arp) = _c * _rp - _s * _rq;                                        \
    (arq) = _s * _rp + _c * _rq;                                        \
    _Pragma("unroll")                                                   \
    for (int _r = 0; _r < 3; _r++) {                                    \
      float _vp = v[3 * _r + (pcol)], _vq = v[3 * _r + (qcol)];         \
      v[3 * _r + (pcol)] = _c * _vp - _s * _vq;                         \
      v[3 * _r + (qcol)] = _s * _vp + _c * _vq;                         \
    }                                                                   \
  }

// SVD-based rotation: 3x3 m[9] (row-major) -> R(9). Branchless throughout.
__device__ __forceinline__ void svd_rotation(const float* m, float* R)
{
    float a00 = m[0]*m[0] + m[3]*m[3] + m[6]*m[6];
    float a01 = m[0]*m[1] + m[3]*m[4] + m[6]*m[7];
    float a02 = m[0]*m[2] + m[3]*m[5] + m[6]*m[8];
    float a11 = m[1]*m[1] + m[4]*m[4] + m[7]*m[7];
    float a12 = m[1]*m[2] + m[4]*m[5] + m[7]*m[8];
    float a22 = m[2]*m[2] + m[5]*m[5] + m[8]*m[8];

    float v[9] = {1.f,0.f,0.f, 0.f,1.f,0.f, 0.f,0.f,1.f};
    #pragma unroll
    for (int sweep = 0; sweep < 5; sweep++) {
        JACOBI_ROT(a00, a11, a01, a02, a12, 0, 1);
        JACOBI_ROT(a00, a22, a02, a01, a12, 0, 2);
        JACOBI_ROT(a11, a22, a12, a01, a02, 1, 2);
    }

    float dd[3] = {a00, a11, a22};
    #pragma unroll
    for (int pass = 0; pass < 3; pass++) {
        const int ii = (pass == 2) ? 1 : 0;   // 0,0,1
        const int jj = (pass == 0) ? 1 : 2;   // 1,2,2
        float di = dd[ii], dj = dd[jj];
        bool sw = di < dj;
        dd[ii] = sw ? dj : di;
        dd[jj] = sw ? di : dj;
        #pragma unroll
        for (int rr = 0; rr < 3; rr++) {
            float a = v[3*rr+ii], b = v[3*rr+jj];
            v[3*rr+ii] = sw ? b : a;
            v[3*rr+jj] = sw ? a : b;
        }
    }

    float v0x = v[0], v0y = v[3], v0z = v[6];
    float v1x = v[1], v1y = v[4], v1z = v[7];
    float v2x = v[2], v2y = v[5], v2z = v[8];

    float u1x = m[0]*v0x + m[1]*v0y + m[2]*v0z;
    float u1y = m[3]*v0x + m[4]*v0y + m[5]*v0z;
    float u1z = m[6]*v0x + m[7]*v0y + m[8]*v0z;
    float n1 = rsqrtf(fmaxf(u1x*u1x + u1y*u1y + u1z*u1z, 1e-30f));
    u1x *= n1; u1y *= n1; u1z *= n1;

    float u2x = m[0]*v1x + m[1]*v1y + m[2]*v1z;
    float u2y = m[3]*v1x + m[4]*v1y + m[5]*v1z;
    float u2z = m[6]*v1x + m[7]*v1y + m[8]*v1z;
    float d12 = u1x*u2x + u1y*u2y + u1z*u2z;
    u2x -= d12 * u1x; u2y -= d12 * u1y; u2z -= d12 * u1z;
    float n2 = rsqrtf(fmaxf(u2x*u2x + u2y*u2y + u2z*u2z, 1e-30f));
    u2x *= n2; u2y *= n2; u2z *= n2;

    float u3x = u1y*u2z - u1z*u2y;
    float u3y = u1z*u2x - u1x*u2z;
    float u3z = u1x*u2y - u1y*u2x;
    float cxv = v1y*v2z - v1z*v2y;
    float cyv = v1z*v2x - v1x*v2z;
    float czv = v1x*v2y - v1y*v2x;
    float detv = v0x*cxv + v0y*cyv + v0z*czv;
    float sg = (detv >= 0.f) ? 1.f : -1.f;
    u3x *= sg; u3y *= sg; u3z *= sg;

    R[0] = u1x*v0x + u2x*v1x + u3x*v2x;
    R[1] = u1x*v0y + u2x*v1y + u3x*v2y;
    R[2] = u1x*v0z + u2x*v1z + u3x*v2z;
    R[3] = u1y*v0x + u2y*v1x + u3y*v2x;
    R[4] = u1y*v0y + u2y*v1y + u3y*v2y;
    R[5] = u1y*v0z + u2y*v1z + u3y*v2z;
    R[6] = u1z*v0x + u2z*v1x + u3z*v2x;
    R[7] = u1z*v0y + u2z*v1y + u3z*v2y;
    R[8] = u1z*v0z + u2z*v1z + u3z*v2z;
}

// Byte address of owner-lane o's sub-slot so (so=0..2). XOR touches only bits
// 4-5 -> stays inside o's own 64B slot -> bijective (verified correct in R8).
// For fixed so, lanes o=0..7 cover all 8 bank-groups -> b128 LDS floor.
__device__ __forceinline__ int slotAddr(int o, int so) {
    return (o << 6) | ((so << 4) ^ ((o & 6) << 3));
}

__global__ __launch_bounds__(TPB) void align_kernel(
    const float* __restrict__ traj,
    const float* __restrict__ ref_pos,
    const int* __restrict__ align_idx,
    float* __restrict__ out,
    int B)
{
    __shared__ float4 s_rmap[NATOMS];                  // 2 KB
    __shared__ __align__(16) char  s_stage[4096];      // 64 lanes x 64B slots
    __shared__ __align__(16) float s_cov[FRW][20];     // cov+xc -> R+xc, 80B rows

    const int l    = threadIdx.x;          // lane 0..63
    const int lf   = l & 31;               // lane within frame half
    const int half = l >> 5;               // which frame of the tile
    const int q0   = blockIdx.x * (FRW * 96);   // first float4 of this wave's batch
    const int lim  = B * 96;
    const float4 z4 = make_float4(0.f, 0.f, 0.f, 0.f);
    const float4* __restrict__ gin  = (const float4*)traj;
    float4* __restrict__       gout = (float4*)out;

    // ---------- rmap build (all 64 lanes; W->W same-wave is ordered) ----------
    {
        s_rmap[l]          = z4;
        s_rmap[l + NALIGN] = z4;
        int idx = align_idx[l];
        float rx = ref_pos[idx * 3 + 0];
        float ry = ref_pos[idx * 3 + 1];
        float rz = ref_pos[idx * 3 + 2];
        float sx = rx, sy = ry, sz = rz;
        #pragma unroll
        for (int off = 32; off >= 1; off >>= 1) {
            sx += __shfl_xor(sx, off);
            sy += __shfl_xor(sy, off);
            sz += __shfl_xor(sz, off);
        }
        const float inv = 1.0f / (float)NALIGN;
        int slot = ((idx & 3) << 5) | (idx >> 2);
        s_rmap[slot] = make_float4(rx - sx*inv, ry - sy*inv, rz - sz*inv, 1.0f);
    }

    // ---------- phase-1 prologue: prefetch tiles 0..PF-1 into registers ------
    float4 st[PF][3];
    #pragma unroll
    for (int p = 0; p < PF; p++)
        #pragma unroll
        for (int c = 0; c < 3; c++) {
            int gq = q0 + (p * 3 + c) * 64 + l;
            st[p][c] = (gq < lim) ? gin[gq] : z4;
        }

    // ================= PHASE 1: stream + covariance (no barriers) ============
    #pragma unroll 1
    for (int tb = 0; tb < TILES; tb += PF) {
        #pragma unroll
        for (int p = 0; p < PF; p++) {
            const int t = tb + p;
            // scatter raw float4s into swizzled atom slots
            #pragma unroll
            for (int c = 0; c < 3; c++) {
                int q  = c * 64 + l;
                int o  = q / 3, so = q - 3 * o;
                *(float4*)(s_stage + slotAddr(o, so)) = st[p][c];
            }
            LDS_FENCE();                                  // W -> R
            float4 u0 = *(const float4*)(s_stage + slotAddr(l, 0));
            float4 u1 = *(const float4*)(s_stage + slotAddr(l, 1));
            float4 u2 = *(const float4*)(s_stage + slotAddr(l, 2));
            LDS_FENCE();                                  // R done before next W (WAR)
            float x[4] = { u0.x, u0.w, u1.z, u2.y };
            float y[4] = { u0.y, u1.x, u1.w, u2.z };
            float z[4] = { u0.z, u1.y, u2.x, u2.w };

            float sx = 0.f, sy = 0.f, sz = 0.f;
            float c9[9] = {0.f,0.f,0.f,0.f,0.f,0.f,0.f,0.f,0.f};
            #pragma unroll
            for (int j = 0; j < 4; j++) {
                float4 rm = s_rmap[(j << 5) | lf];
                sx += rm.w * x[j]; sy += rm.w * y[j]; sz += rm.w * z[j];
                c9[0] += x[j]*rm.x; c9[1] += x[j]*rm.y; c9[2] += x[j]*rm.z;
                c9[3] += y[j]*rm.x; c9[4] += y[j]*rm.y; c9[5] += y[j]*rm.z;
                c9[6] += z[j]*rm.x; c9[7] += z[j]*rm.y; c9[8] += z[j]*rm.z;
            }
            #pragma unroll
            for (int off = 16; off >= 1; off >>= 1) {
                sx += __shfl_xor(sx, off);
                sy += __shfl_xor(sy, off);
                sz += __shfl_xor(sz, off);
                #pragma unroll
                for (int jj = 0; jj < 9; jj++) c9[jj] += __shfl_xor(c9[jj], off);
            }
            if (lf == 0) {
                int fr = 2 * t + half;
                const float inv = 1.0f / (float)NALIGN;
                *(float4*)&s_cov[fr][0] = make_float4(c9[0], c9[1], c9[2], c9[3]);
                *(float4*)&s_cov[fr][4] = make_float4(c9[4], c9[5], c9[6], c9[7]);
                *(float4*)&s_cov[fr][8] = make_float4(c9[8], sx*inv, sy*inv, sz*inv);
            }
            // prefetch tile t+PF into this register buffer (stays in flight)
            if (t + PF < TILES) {
                #pragma unroll
                for (int c = 0; c < 3; c++) {
                    int gq = q0 + ((t + PF) * 3 + c) * 64 + l;
                    st[p][c] = (gq < lim) ? gin[gq] : z4;
                }
            }
        }
    }

    // ================= PHASE 2: 32 lane-dense SVDs in this wave ==============
    LDS_FENCE();                                          // cov rows visible
    {
        int fr = lf;                      // lanes 32..63 duplicate (harmless)
        float4 a0 = *(const float4*)&s_cov[fr][0];
        float4 a1 = *(const float4*)&s_cov[fr][4];
        float4 a2 = *(const float4*)&s_cov[fr][8];
        float m[9] = { a0.x, a0.y, a0.z, a0.w, a1.x, a1.y, a1.z, a1.w, a2.x };
        float R[9];
        svd_rotation(m, R);
        LDS_FENCE();                                      // reads done (WAR)
        if (l < 32) {
            *(float4*)&s_cov[fr][0] = make_float4(R[0], R[1], R[2], R[3]);
            *(float4*)&s_cov[fr][4] = make_float4(R[4], R[5], R[6], R[7]);
            *(float4*)&s_cov[fr][8] = make_float4(R[8], a2.y, a2.z, a2.w);
        }
    }
    LDS_FENCE();                                          // R rows visible

    // ---------- phase-3 prologue: re-prefetch tiles 0..PF-1 (L3-hot) ---------
    #pragma unroll
    for (int p = 0; p < PF; p++)
        #pragma unroll
        for (int c = 0; c < 3; c++) {
            int gq = q0 + (p * 3 + c) * 64 + l;
            st[p][c] = (gq < lim) ? gin[gq] : z4;
        }

    // ================= PHASE 3: rotate + stream out (no barriers) ============
    #pragma unroll 1
    for (int tb = 0; tb < TILES; tb += PF) {
        #pragma unroll
        for (int p = 0; p < PF; p++) {
            const int t = tb + p;
            #pragma unroll
            for (int c = 0; c < 3; c++) {
                int q  = c * 64 + l;
                int o  = q / 3, so = q - 3 * o;
                *(float4*)(s_stage + slotAddr(o, so)) = st[p][c];
            }
            LDS_FENCE();                                  // W -> R
            float4 u0 = *(const float4*)(s_stage + slotAddr(l, 0));
            float4 u1 = *(const float4*)(s_stage + slotAddr(l, 1));
            float4 u2 = *(const float4*)(s_stage + slotAddr(l, 2));
            LDS_FENCE();                                  // R done before re-write
            float x[4] = { u0.x, u0.w, u1.z, u2.y };
            float y[4] = { u0.y, u1.x, u1.w, u2.z };
            float z[4] = { u0.z, u1.y, u2.x, u2.w };

            int fr = 2 * t + half;
            float4 a0 = *(const float4*)&s_cov[fr][0];    // broadcast reads
            float4 a1 = *(const float4*)&s_cov[fr][4];
            float4 a2 = *(const float4*)&s_cov[fr][8];
            float R0 = a0.x, R1 = a0.y, R2 = a0.z, R3 = a0.w;
            float R4 = a1.x, R5 = a1.y, R6 = a1.z, R7 = a1.w;
            float R8 = a2.x, xcx = a2.y, xcy = a2.z, xcz = a2.w;

            float ox[4], oy[4], oz[4];
            #pragma unroll
            for (int j = 0; j < 4; j++) {
                float dx = x[j] - xcx, dy = y[j] - xcy, dz = z[j] - xcz;
                ox[j] = dx*R0 + dy*R3 + dz*R6;
                oy[j] = dx*R1 + dy*R4 + dz*R7;
                oz[j] = dx*R2 + dy*R5 + dz*R8;
            }

            *(float4*)(s_stage + slotAddr(l, 0)) = make_float4(ox[0], oy[0], oz[0], ox[1]);
            *(float4*)(s_stage + slotAddr(l, 1)) = make_float4(oy[1], oz[1], ox[2], oy[2]);
            *(float4*)(s_stage + slotAddr(l, 2)) = make_float4(oz[2], ox[3], oy[3], oz[3]);
            LDS_FENCE();                                  // W -> R
            float4 v0, v1, v2;
            {
                int q, o, so;
                q = 0 * 64 + l; o = q / 3; so = q - 3 * o;
                v0 = *(const float4*)(s_stage + slotAddr(o, so));
                q = 1 * 64 + l; o = q / 3; so = q - 3 * o;
                v1 = *(const float4*)(s_stage + slotAddr(o, so));
                q = 2 * 64 + l; o = q / 3; so = q - 3 * o;
                v2 = *(const float4*)(s_stage + slotAddr(o, so));
            }
            LDS_FENCE();                                  // R done before next W
            {
                int gq0 = q0 + (t * 3 + 0) * 64 + l;
                int gq1 = q0 + (t * 3 + 1) * 64 + l;
                int gq2 = q0 + (t * 3 + 2) * 64 + l;
                if (gq0 < lim) gout[gq0] = v0;
                if (gq1 < lim) gout[gq1] = v1;
                if (gq2 < lim) gout[gq2] = v2;
            }
            if (t + PF < TILES) {
                #pragma unroll
                for (int c = 0; c < 3; c++) {
                    int gq = q0 + ((t + PF) * 3 + c) * 64 + l;
                    st[p][c] = (gq < lim) ? gin[gq] : z4;
                }
            }
        }
    }
}

extern "C" void kernel_launch(void* const* d_in, const int* in_sizes, int n_in,
                              void* d_out, int out_size, void* d_ws, size_t ws_size,
                              hipStream_t stream) {
    const float* traj      = (const float*)d_in[0];
    const float* ref_pos   = (const float*)d_in[1];
    const int*   align_idx = (const int*)d_in[2];
    float*       out       = (float*)d_out;

    int B = in_sizes[0] / (NATOMS * 3);
    int grid = (B + FRW - 1) / FRW;
    align_kernel<<<grid, TPB, 0, stream>>>(traj, ref_pos, align_idx, out, B);
}